// Round 8
// baseline (29.564 us; speedup 1.0000x reference)
//
#include <hip/hip_runtime.h>

// PhysConstrainedLES: fused divergence + pressure-Poisson RHS stencils.
// uPred: [B,2,H,W] f32, pPred: [B,1,H,W] f32
// out:  div [B,510,512] then pstar [B,510,510], concatenated flat, f32.
//
// R8: 4 cols x 2 output rows per thread (128-thr block, 8160 blocks).
// Each thread loads 4 input rows x {u,v,p} = 12 float4 loads, ALL
// lane-contiguous per instruction (wc = tid*4) -- R6's regression was
// gapped per-instruction access (wc = lane*8), not occupancy.
// Halos via intra-wave shuffles; wave-edge lanes fix up with (clamped)
// scalar loads, which also realizes replicate-pad at the true image edge.
// div stores non-temporal (full-line coverage; R7 verified no inflation).

#define BN 32
#define HH 512
#define WW 512
#define OH 510
#define OW2 510
#define NPAIR 255
#define NBLK (NPAIR * BN)   // 8160, divisible by 8

typedef float f32x4 __attribute__((ext_vector_type(4)));

__device__ __forceinline__ float clip1(float x) {
    return fminf(fmaxf(x, -1.0f), 1.0f);
}

__global__ __launch_bounds__(128) void pcles_kernel(
    const float* __restrict__ u_,   // [B,2,H,W]
    const float* __restrict__ p_,   // [B,1,H,W]
    float* __restrict__ div_out,    // [B,510,512]
    float* __restrict__ ps_out)     // [B,510,510]
{
    // bijective XCD swizzle: consecutive row-pairs of one batch on one XCD.
    const int bid = blockIdx.x;
    const int nb  = (bid & 7) * (NBLK / 8) + (bid >> 3);
    const int b   = nb / NPAIR;
    const int rp  = nb % NPAIR;
    const int hA  = rp * 2;          // output rows hA, hA+1; input rows hA..hA+3

    const int tid  = (int)threadIdx.x;
    const int wc   = tid * 4;        // 0..508 (contiguous per instruction)
    const int lane = tid & 63;

    const float* ub = u_ + (size_t)b * 2 * HH * WW;
    const float* vb = ub + HH * WW;
    const float* pb = p_ + (size_t)b * HH * WW;
    const float* ur = ub + hA * WW;  // input row hA
    const float* vr = vb + hA * WW;
    const float* pr = pb + hA * WW;

    // 12 independent, perfectly coalesced float4 loads (rows hA..hA+3)
    const float4 tu0 = *(const float4*)(ur + wc);
    const float4 tu1 = *(const float4*)(ur + WW + wc);
    const float4 tu2 = *(const float4*)(ur + 2 * WW + wc);
    const float4 tu3 = *(const float4*)(ur + 3 * WW + wc);
    const float4 tv0 = *(const float4*)(vr + wc);
    const float4 tv1 = *(const float4*)(vr + WW + wc);
    const float4 tv2 = *(const float4*)(vr + 2 * WW + wc);
    const float4 tv3 = *(const float4*)(vr + 3 * WW + wc);
    const float4 tp0 = *(const float4*)(pr + wc);
    const float4 tp1 = *(const float4*)(pr + WW + wc);
    const float4 tp2 = *(const float4*)(pr + 2 * WW + wc);
    const float4 tp3 = *(const float4*)(pr + 3 * WW + wc);

    // halo columns via intra-wave shuffles (20 total)
    float uL1 = __shfl_up(tu1.w, 1);     // row hA+1, col wc-1
    float uL2 = __shfl_up(tu2.w, 1);     // row hA+2, col wc-1
    float uR0 = __shfl_down(tu0.x, 1);   // row hA,   col wc+4
    float uR1 = __shfl_down(tu1.x, 1);   // row hA+1, col wc+4
    float uR2 = __shfl_down(tu2.x, 1);   // row hA+2, col wc+4
    float uR3 = __shfl_down(tu3.x, 1);   // row hA+3, col wc+4
    float uS1 = __shfl_down(tu1.y, 1);   // row hA+1, col wc+5
    float uS2 = __shfl_down(tu2.y, 1);   // row hA+2, col wc+5
    float vR0 = __shfl_down(tv0.x, 1);
    float vR1 = __shfl_down(tv1.x, 1);
    float vR2 = __shfl_down(tv2.x, 1);
    float vR3 = __shfl_down(tv3.x, 1);
    float vS1 = __shfl_down(tv1.y, 1);
    float vS2 = __shfl_down(tv2.y, 1);
    float pR0 = __shfl_down(tp0.x, 1);
    float pR1 = __shfl_down(tp1.x, 1);
    float pR2 = __shfl_down(tp2.x, 1);
    float pR3 = __shfl_down(tp3.x, 1);
    float pS1 = __shfl_down(tp1.y, 1);
    float pS2 = __shfl_down(tp2.y, 1);

    // wave-edge fixups (clamped indices give replicate-pad at true edges;
    // interior wave boundaries load the real neighbor column)
    const int cL = (wc > 0) ? wc - 1 : 0;
    const int c4 = (wc + 4 < WW) ? wc + 4 : WW - 1;
    const int c5 = (wc + 5 < WW) ? wc + 5 : WW - 1;
    if (lane == 0) {
        uL1 = ur[WW + cL];
        uL2 = ur[2 * WW + cL];
    }
    if (lane == 63) {
        uR0 = ur[c4]; uR1 = ur[WW + c4]; uR2 = ur[2 * WW + c4]; uR3 = ur[3 * WW + c4];
        uS1 = ur[WW + c5]; uS2 = ur[2 * WW + c5];
        vR0 = vr[c4]; vR1 = vr[WW + c4]; vR2 = vr[2 * WW + c4]; vR3 = vr[3 * WW + c4];
        vS1 = vr[WW + c5]; vS2 = vr[2 * WW + c5];
        pR0 = pr[c4]; pR1 = pr[WW + c4]; pR2 = pr[2 * WW + c4]; pR3 = pr[3 * WW + c4];
        pS1 = pr[WW + c5]; pS2 = pr[2 * WW + c5];
    }

    // constant-indexed windows
    const float uw0[5] = {tu0.x, tu0.y, tu0.z, tu0.w, uR0};                   // cols wc..wc+4
    const float uw1[7] = {uL1, tu1.x, tu1.y, tu1.z, tu1.w, uR1, uS1};         // cols wc-1..wc+5
    const float uw2[7] = {uL2, tu2.x, tu2.y, tu2.z, tu2.w, uR2, uS2};         // cols wc-1..wc+5
    const float uw3[5] = {tu3.x, tu3.y, tu3.z, tu3.w, uR3};
    const float vw0[5] = {tv0.x, tv0.y, tv0.z, tv0.w, vR0};                   // cols wc..wc+4
    const float vw1[6] = {tv1.x, tv1.y, tv1.z, tv1.w, vR1, vS1};              // cols wc..wc+5
    const float vw2[6] = {tv2.x, tv2.y, tv2.z, tv2.w, vR2, vS2};
    const float vw3[5] = {tv3.x, tv3.y, tv3.z, tv3.w, vR3};
    const float pw0[5] = {tp0.x, tp0.y, tp0.z, tp0.w, pR0};
    const float pw1[6] = {tp1.x, tp1.y, tp1.z, tp1.w, pR1, pS1};
    const float pw2[6] = {tp2.x, tp2.y, tp2.z, tp2.w, pR2, pS2};
    const float pw3[5] = {tp3.x, tp3.y, tp3.z, tp3.w, pR3};

    float dvA[4], psA[4], dvB[4], psB[4];
    #pragma unroll
    for (int j = 0; j < 4; ++j) {
        // ---- output row A (h = hA; mid input row hA+1) ----
        {
            const float dudx = (uw1[j + 2] - uw1[j]) * 50.0f;
            const float dvdy = (vw2[j] - vw0[j]) * 50.0f;
            dvA[j] = clip1(0.01f * (dvdy + dudx));

            const float pc  = pw1[j + 1];
            const float ddp = (pw1[j] - 2.0f * pc + pw1[j + 2]) * 1.0e4f
                            + (pw0[j + 1] - 2.0f * pc + pw2[j + 1]) * 1.0e4f;
            const float ux = (uw1[j + 3] - uw1[j + 1]) * 50.0f;
            const float uy = (uw2[j + 2] - uw0[j + 1]) * 50.0f;
            const float vx = (vw1[j + 2] - vw1[j]) * 50.0f;
            const float vy = (vw2[j + 1] - vw0[j + 1]) * 50.0f;
            const float rhs = ux * ux + 2.0f * uy * vx + vy * vy;
            psA[j] = clip1(1.0e-4f * (ddp + rhs));
        }
        // ---- output row B (h = hA+1; mid input row hA+2) ----
        {
            const float dudx = (uw2[j + 2] - uw2[j]) * 50.0f;
            const float dvdy = (vw3[j] - vw1[j]) * 50.0f;
            dvB[j] = clip1(0.01f * (dvdy + dudx));

            const float pc  = pw2[j + 1];
            const float ddp = (pw2[j] - 2.0f * pc + pw2[j + 2]) * 1.0e4f
                            + (pw1[j + 1] - 2.0f * pc + pw3[j + 1]) * 1.0e4f;
            const float ux = (uw2[j + 3] - uw2[j + 1]) * 50.0f;
            const float uy = (uw3[j + 1] - uw1[j + 2]) * 50.0f;
            const float vx = (vw2[j + 2] - vw2[j]) * 50.0f;
            const float vy = (vw3[j + 1] - vw1[j + 1]) * 50.0f;
            const float rhs = ux * ux + 2.0f * uy * vx + vy * vy;
            psB[j] = clip1(1.0e-4f * (ddp + rhs));
        }
    }

    // div: non-temporal full-line stores (lanes contiguous, 1KB/wave-instr)
    float* drA = div_out + ((size_t)b * OH + hA) * WW + wc;
    f32x4 a = {dvA[0], dvA[1], dvA[2], dvA[3]};
    f32x4 c = {dvB[0], dvB[1], dvB[2], dvB[3]};
    __builtin_nontemporal_store(a, (f32x4*)drA);
    __builtin_nontemporal_store(c, (f32x4*)(drA + WW));

    // pstar: plain stores (rows 2040B, 8B-aligned)
    float* pwA = ps_out + ((size_t)b * OH + hA) * OW2 + wc;
    *(float2*)pwA = make_float2(psA[0], psA[1]);
    if (wc + 2 < OW2) *(float2*)(pwA + 2) = make_float2(psA[2], psA[3]);
    float* pwB = pwA + OW2;
    *(float2*)pwB = make_float2(psB[0], psB[1]);
    if (wc + 2 < OW2) *(float2*)(pwB + 2) = make_float2(psB[2], psB[3]);
}

extern "C" void kernel_launch(void* const* d_in, const int* in_sizes, int n_in,
                              void* d_out, int out_size, void* d_ws, size_t ws_size,
                              hipStream_t stream) {
    const float* uPred = (const float*)d_in[0];
    const float* pPred = (const float*)d_in[1];
    float* div_out = (float*)d_out;
    float* ps_out  = div_out + (size_t)BN * OH * WW;

    pcles_kernel<<<dim3(NBLK), dim3(128), 0, stream>>>(uPred, pPred, div_out, ps_out);
}